// Round 7
// baseline (184.676 us; speedup 1.0000x reference)
//
#include <hip/hip_runtime.h>
#include <math.h>
#include <stdint.h>

// ---------------- model constants ----------------
#define BATCH 65536
#define TB 64            // rows per block: 2 m-tiles x 32 rows; 2 waves per tile (k-split)

typedef __fp16   fp16x2  __attribute__((ext_vector_type(2)));   // cvt_pkrtz result
typedef _Float16 half4   __attribute__((ext_vector_type(4)));
typedef _Float16 half8   __attribute__((ext_vector_type(8)));
typedef float    floatx16 __attribute__((ext_vector_type(16)));

// strides (elements)
#define SH 68            // hH: 64 cols + pad (f32 words for partials, halves for f16)
#define SM 130           // hM: 129 cols + 1

// packed-weight geometry (f16), FRAGMENT-ORDERED for 32x32x16 (same as R0):
//   element (ks, nt, lane, j) at ((ks*NT + nt)*512) + lane*8 + j
//   maps to B[k = ks*16 + (lane>>5)*8 + j][n = nt*32 + (lane&31)]
#define WIN 2048          // stage1: 2 ksteps x 2 ntiles x 512
#define KSA 36            // a: 32 spline ksteps + 4 silu
#define KSB 74            // b: 65 spline ksteps (1032 real k) + 9 silu (129 real)
#define WA (KSA*5*512)    // 92160
#define WB (KSB*2*512)    // 75776
#define WTOT (WIN + 2*(WA+WB))   // 337920 halfs = 675840 B of d_ws

// ---------------------------------------------------------------------------
// setup: pack all weights f16 in 32x32-fragment order (unchanged from R0).
// ---------------------------------------------------------------------------
__global__ void setup_weights(
    const float* __restrict__ W_in,
    const float* __restrict__ c0a, const float* __restrict__ sb0a, const float* __restrict__ ss0a,
    const float* __restrict__ c0b, const float* __restrict__ sb0b, const float* __restrict__ ss0b,
    const float* __restrict__ c1a, const float* __restrict__ sb1a, const float* __restrict__ ss1a,
    const float* __restrict__ c1b, const float* __restrict__ sb1b, const float* __restrict__ ss1b,
    _Float16* __restrict__ wt) {
  int idx = blockIdx.x * 256 + threadIdx.x;
  if (idx >= WTOT) return;
  float v = 0.0f;
  if (idx < WIN) {                        // W_in [32][64]: (ks*2+nt)*512 order
    int ks = idx >> 10; int nt = (idx >> 9) & 1;
    int q = idx & 511;  int l = q >> 3;   int j = q & 7;
    int n = nt*32 + (l & 31);
    int k = ks*16 + (l >> 5)*8 + j;
    v = W_in[k*64 + n];
  } else {
    int e2   = idx - WIN;
    int pair = (e2 >= WA + WB) ? 1 : 0;
    int e    = e2 - pair * (WA + WB);
    if (e < WA) {                         // a-type: I=64, O=129 (5 n-tiles)
      const float* coef = pair ? c1a : c0a;
      const float* sb   = pair ? sb1a : sb0a;
      const float* ss   = pair ? ss1a : ss0a;
      int ks = e / 2560; int r = e - ks*2560;
      int nt = r >> 9;   int q = r & 511;
      int l  = q >> 3;   int j = q & 7;
      int n  = nt*32 + (l & 31);
      int k  = ks*16 + (l >> 5)*8 + j;    // k < 576
      if (n < 129) {
        if (k < 512) { int i = k >> 3, p = k & 7; v = ss[i*129+n] * coef[(i*129+n)*8 + p]; }
        else         { int i = k - 512; if (i < 64) v = sb[i*129+n]; }
      }
    } else {                              // b-type: I=129, O=64 (2 n-tiles)
      const float* coef = pair ? c1b : c0b;
      const float* sb   = pair ? sb1b : sb0b;
      const float* ss   = pair ? ss1b : ss0b;
      int eb = e - WA;
      int ks = eb >> 10; int r = eb & 1023;
      int nt = r >> 9;   int q = r & 511;
      int l  = q >> 3;   int j = q & 7;
      int n  = nt*32 + (l & 31);
      int k  = ks*16 + (l >> 5)*8 + j;    // k < 1184
      if (k < 1032)      { int i = k >> 3, p = k & 7; v = ss[i*64+n] * coef[(i*64+n)*8 + p]; }
      else if (k >= 1040){ int s = k - 1040; if (s < 129) v = sb[s*64+n]; }
      // k in [1032,1040) and s >= 129: dead pad slots -> 0
    }
  }
  wt[idx] = (_Float16)v;
}

// ---------------------------------------------------------------------------
// feat8: 8 B-spline basis values of x as a ready A-fragment (unchanged).
// NaN/huge input -> m guard fails -> returns all-zero fragment (safe).
// ---------------------------------------------------------------------------
__device__ __forceinline__ half8 feat8(float x) {
  float s  = fmaf(x, 2.5f, 5.5f);
  float mf = floorf(s);
  int   m  = (int)mf;
  float u  = s - mf;
  float t  = 1.0f - u;
  float u2 = u*u;
  float t2 = t*t;
  float w0 = t2 * (t * (1.0f/6.0f));
  float w3 = u2 * (u * (1.0f/6.0f));
  float w1 = fmaf(u2, fmaf(0.5f, u, -1.0f), 2.0f/3.0f);
  float w2 = fmaf(t2, fmaf(0.5f, t, -1.0f), 2.0f/3.0f);
  union { fp16x2 h2[2]; uint64_t u64; } P;
  P.h2[0] = __builtin_amdgcn_cvt_pkrtz(w0, w1);
  P.h2[1] = __builtin_amdgcn_cvt_pkrtz(w2, w3);
  uint64_t T = ((unsigned)m <= 10u) ? P.u64 : 0ull;
  int A = (m << 4) - 48;
  uint64_t L  = T << (A & 63);
  uint64_t R_ = T >> ((-A) & 63);
  uint64_t q0 = (A >= 0) ? ((A < 64) ? L : 0ull) : R_;
  uint64_t q1 = (A >= 64) ? L : ((A > 0) ? R_ : 0ull);
  union { uint64_t q[2]; half8 h; } R;
  R.q[0] = q0; R.q[1] = q1;
  return R.h;
}

__device__ __forceinline__ float extract_half(uint32_t w, int khs) {
  union { uint32_t u; _Float16 h[2]; } cv;
  cv.u = w >> khs;
  return (float)cv.h[0];
}

__device__ __forceinline__ float silu(float x) {
  return x * __builtin_amdgcn_rcpf(1.0f + __expf(-x));
}

// ---------------------------------------------------------------------------
// half of one KAN layer's k-range: ksteps KS0..KS0+2*NPAIR(+REM)(+NSIL silu).
// Spline ksteps in pairs (one ds b64 h-read per pair), depth-2 zero-copy B
// pipeline (proven optimal in R3). Accumulates into acc (caller-owned).
// ---------------------------------------------------------------------------
template<int KS0, int NPAIR, int REM, int NSIL, int KSPL, int KSIL, int NT, int SIN>
__device__ __forceinline__ void kan_half(
    const _Float16* __restrict__ hinw, const _Float16* __restrict__ wtl,
    floatx16 (&acc)[NT], int lane) {
  constexpr int KTOT = KSPL + KSIL;
  const int ln  = lane & 31;
  const int kh  = lane >> 5;
  const int khs = kh << 4;
  const half8* __restrict__ bp = (const half8*)wtl + lane;   // +lane*16B
  #pragma unroll
  for (int j = 0; j < NT; ++j)
    #pragma unroll
    for (int e = 0; e < 16; ++e) acc[j][e] = 0.0f;

  half8 B0v[NT], B1v[NT];                   // depth-2, zero-copy slots
  #pragma unroll
  for (int j = 0; j < NT; ++j) B0v[j] = bp[((KS0    )*NT + j)*64];
  #pragma unroll
  for (int j = 0; j < NT; ++j) B1v[j] = bp[((KS0 + 1)*NT + j)*64];

  // ---- spline pairs: ksteps ks0, ks0+1; inputs 2ks0+kh, 2ks0+2+kh ----
  #pragma unroll 1
  for (int c = 0; c < NPAIR; ++c) {
    const int ks0 = KS0 + 2*c;
    union { half4 v; uint32_t d[2]; } hq;
    hq.v = *(const half4*)&hinw[ln*SIN + 2*ks0];
    half8 A0 = feat8(extract_half(hq.d[0], khs));
    half8 A1 = feat8(extract_half(hq.d[1], khs));
    #pragma unroll
    for (int j = 0; j < NT; ++j)
      acc[j] = __builtin_amdgcn_mfma_f32_32x32x16_f16(A0, B0v[j], acc[j], 0, 0, 0);
    #pragma unroll
    for (int j = 0; j < NT; ++j) B0v[j] = bp[((ks0 + 2)*NT + j)*64];
    #pragma unroll
    for (int j = 0; j < NT; ++j)
      acc[j] = __builtin_amdgcn_mfma_f32_32x32x16_f16(A1, B1v[j], acc[j], 0, 0, 0);
    #pragma unroll
    for (int j = 0; j < NT; ++j) B1v[j] = bp[((ks0 + 3)*NT + j)*64];
  }

  // ---- spline remainder (layer-b high half: ks = 64) ----
  if constexpr (REM) {
    constexpr int ks = KS0 + 2*NPAIR;
    uint32_t w = *(const uint32_t*)&hinw[ln*SIN + 2*ks];
    half8 A = feat8(extract_half(w, khs));
    #pragma unroll
    for (int j = 0; j < NT; ++j)
      acc[j] = __builtin_amdgcn_mfma_f32_32x32x16_f16(A, B0v[j], acc[j], 0, 0, 0);
    #pragma unroll
    for (int j = 0; j < NT; ++j) B0v[j] = bp[((ks + 2)*NT + j)*64];
  }

  // ---- silu ksteps (fully unrolled; slot parity continues the sequence) ----
  #pragma unroll
  for (int sk = 0; sk < NSIL; ++sk) {
    const int ksl = KSPL + sk;
    half8 h8 = *(const half8*)&hinw[ln*SIN + sk*16 + kh*8];
    union { fp16x2 h2[4]; half8 v; } Au;
    #pragma unroll
    for (int e = 0; e < 4; ++e) {
      float s0 = silu((float)h8[2*e]);
      float s1 = silu((float)h8[2*e + 1]);
      Au.h2[e] = __builtin_amdgcn_cvt_pkrtz(s0, s1);
    }
    const int nks = (ksl + 2 < KTOT) ? (ksl + 2) : (KTOT - 1);  // clamp: dead loads
    if (((ksl - KS0) & 1) == 0) {
      #pragma unroll
      for (int j = 0; j < NT; ++j)
        acc[j] = __builtin_amdgcn_mfma_f32_32x32x16_f16(Au.v, B0v[j], acc[j], 0, 0, 0);
      #pragma unroll
      for (int j = 0; j < NT; ++j) B0v[j] = bp[(nks*NT + j)*64];
    } else {
      #pragma unroll
      for (int j = 0; j < NT; ++j)
        acc[j] = __builtin_amdgcn_mfma_f32_32x32x16_f16(Au.v, B1v[j], acc[j], 0, 0, 0);
      #pragma unroll
      for (int j = 0; j < NT; ++j) B1v[j] = bp[(nks*NT + j)*64];
    }
  }
}

// ---------------------------------------------------------------------------
// one full KAN layer with 2-wave k-split. THREE-PHASE race-free combine:
//   P1: store f32 partials (cols the PARTNER finalizes)        -> barrier
//   P2: stage partner partials for MY cols into REGISTERS      -> barrier
//   P3: write f16 finals in place (f32 buffer now dead)        -> barrier
// The R6 bug was overlapping P2 reads with P3 writes (f16 overlays f32).
// ---------------------------------------------------------------------------
template<int KSPL, int KSIL, int NT, int JS, int SIN, int O, int SF, int S16,
         int N0, int K1, int N1, int R1, int S1, bool TAILZ>
__device__ __forceinline__ void kan_layer_ks(
    const _Float16* __restrict__ hinw, float* __restrict__ foutF,
    _Float16* __restrict__ hout16, const _Float16* __restrict__ wtl,
    const float* __restrict__ bias, int lane, int role) {
  constexpr int NJ0 = JS;        // tiles role0 finalizes (j < JS)
  constexpr int NJ1 = NT - JS;   // tiles role1 finalizes (j >= JS)
  constexpr int NJM = (NJ0 > NJ1) ? NJ0 : NJ1;
  const int ln = lane & 31;
  const int kh = lane >> 5;
  floatx16 acc[NT];
  if (role == 0) kan_half<0,  N0, 0,  0,  KSPL, KSIL, NT, SIN>(hinw, wtl, acc, lane);
  else           kan_half<K1, N1, R1, S1, KSPL, KSIL, NT, SIN>(hinw, wtl, acc, lane);

  // ---- P1: store partials for the partner's columns ----
  if (role == 0) {
    #pragma unroll
    for (int jj = 0; jj < NJ1; ++jj) {
      const int j = JS + jj;
      int col = j*32 + ln;
      if (col < O) {
        #pragma unroll
        for (int r = 0; r < 16; ++r) {
          int row = (r & 3) + 8*(r >> 2) + 4*kh;
          foutF[row*SF + col] = acc[j][r];
        }
      }
    }
  } else {
    #pragma unroll
    for (int jj = 0; jj < NJ0; ++jj) {
      int col = jj*32 + ln;                  // always < 96 <= O
      #pragma unroll
      for (int r = 0; r < 16; ++r) {
        int row = (r & 3) + 8*(r >> 2) + 4*kh;
        foutF[row*SF + col] = acc[jj][r];
      }
    }
  }
  __syncthreads();

  // ---- P2: stage partner partials for MY columns into registers ----
  float pre[NJM][16];
  if (role == 0) {
    #pragma unroll
    for (int jj = 0; jj < NJ0; ++jj) {
      int col = jj*32 + ln;                  // always < O
      #pragma unroll
      for (int r = 0; r < 16; ++r) {
        int row = (r & 3) + 8*(r >> 2) + 4*kh;
        pre[jj][r] = foutF[row*SF + col];
      }
    }
  } else {
    #pragma unroll
    for (int jj = 0; jj < NJ1; ++jj) {
      const int j = JS + jj;
      int col = j*32 + ln;
      bool ok = (col < O);
      #pragma unroll
      for (int r = 0; r < 16; ++r) {
        int row = (r & 3) + 8*(r >> 2) + 4*kh;
        pre[jj][r] = ok ? foutF[row*SF + col] : 0.0f;
      }
    }
  }
  __syncthreads();

  // ---- P3: write f16 finals (all f32 reads complete; overlay now safe) ----
  if (role == 0) {
    #pragma unroll
    for (int jj = 0; jj < NJ0; ++jj) {
      int col = jj*32 + ln;
      float bv = bias[col];
      #pragma unroll
      for (int r = 0; r < 16; ++r) {
        int row = (r & 3) + 8*(r >> 2) + 4*kh;
        hout16[row*S16 + col] = (_Float16)(pre[jj][r] + acc[jj][r] + bv);
      }
    }
  } else {
    #pragma unroll
    for (int jj = 0; jj < NJ1; ++jj) {
      const int j = JS + jj;
      int col = j*32 + ln;
      if (col < O) {
        float bv = bias[col];
        #pragma unroll
        for (int r = 0; r < 16; ++r) {
          int row = (r & 3) + 8*(r >> 2) + 4*kh;
          hout16[row*S16 + col] = (_Float16)(pre[jj][r] + acc[j][r] + bv);
        }
      } else if (O == 129 && col == 129) {   // pad col: keep finite zero
        #pragma unroll
        for (int r = 0; r < 16; ++r) {
          int row = (r & 3) + 8*(r >> 2) + 4*kh;
          hout16[row*S16 + col] = (_Float16)0.0f;
        }
      }
    }
    if (TAILZ && lane < 16)                  // tail halves read by b128 overrun
      hout16[32*S16 + lane] = (_Float16)0.0f;
  }
  __syncthreads();
}

// ---------------------------------------------------------------------------
// fused forward: 2 m-tiles per 256-thread block, each tile = 2 waves k-split.
// 4096 waves total (2x baseline TLP), B traffic per tile UNCHANGED.
// LDS 50688 B -> 3 blocks/CU -> 3 waves/SIMD at ~half work/wave.
// ---------------------------------------------------------------------------
extern "C" __global__ void __launch_bounds__(256, 3)
kan_forward(const float* __restrict__ x, const float* __restrict__ b_in,
            const float* __restrict__ W_out, const _Float16* __restrict__ wt,
            const float* __restrict__ bias0a, const float* __restrict__ bias0b,
            const float* __restrict__ bias1a, const float* __restrict__ bias1b,
            float* __restrict__ out) {
  __shared__ __align__(16) float hMf[2][32*SM];   // 2 x 16640 B (f32 partials; f16 overlay)
  __shared__ __align__(16) float hHf[2][32*SH];   // 2 x  8704 B
  const int t    = threadIdx.x;
  const int wv   = t >> 6;
  const int lane = t & 63;
  const int ln   = lane & 31;
  const int kh   = lane >> 5;
  const int p    = wv >> 1;          // tile index within block
  const int role = wv & 1;           // 0 = low-k half, 1 = high-k half
  float*     hMfp = hMf[p];
  float*     hHfp = hHf[p];
  _Float16*  hM16 = (_Float16*)hMfp;
  _Float16*  hH16 = (_Float16*)hHfp;
  const int rbase = blockIdx.x * TB + p * 32;

  // stage 1: hH = relu(x @ W_in + b_in). k=32 full per wave; n-tile = role.
  {
    const float* xr = &x[(size_t)(rbase + ln)*32 + kh*8];
    float4 v0 = *(const float4*)&xr[0];
    float4 v1 = *(const float4*)&xr[4];
    float4 v2 = *(const float4*)&xr[16];
    float4 v3 = *(const float4*)&xr[20];
    union { fp16x2 h2[4]; half8 h8; } A0, A1;
    A0.h2[0] = __builtin_amdgcn_cvt_pkrtz(v0.x, v0.y);
    A0.h2[1] = __builtin_amdgcn_cvt_pkrtz(v0.z, v0.w);
    A0.h2[2] = __builtin_amdgcn_cvt_pkrtz(v1.x, v1.y);
    A0.h2[3] = __builtin_amdgcn_cvt_pkrtz(v1.z, v1.w);
    A1.h2[0] = __builtin_amdgcn_cvt_pkrtz(v2.x, v2.y);
    A1.h2[1] = __builtin_amdgcn_cvt_pkrtz(v2.z, v2.w);
    A1.h2[2] = __builtin_amdgcn_cvt_pkrtz(v3.x, v3.y);
    A1.h2[3] = __builtin_amdgcn_cvt_pkrtz(v3.z, v3.w);
    const half8* bp = (const half8*)wt + lane;
    floatx16 a;
    #pragma unroll
    for (int e = 0; e < 16; ++e) a[e] = 0.0f;
    a = __builtin_amdgcn_mfma_f32_32x32x16_f16(A0.h8, bp[role*64],       a, 0, 0, 0);
    a = __builtin_amdgcn_mfma_f32_32x32x16_f16(A1.h8, bp[(2 + role)*64], a, 0, 0, 0);
    int col = role*32 + ln;
    float bv = b_in[col];
    #pragma unroll
    for (int r = 0; r < 16; ++r) {
      int row = (r & 3) + 8*(r >> 2) + 4*kh;
      hH16[row*SH + col] = (_Float16)fmaxf(a[r] + bv, 0.0f);
    }
  }
  __syncthreads();

  // layer-a: KTOT=36 -> role0 ks 0..17 (9 pairs), role1 ks 18..35 (7 pairs + 4 silu)
  // layer-b: KTOT=74 -> role0 ks 0..37 (19 pairs), role1 ks 38..73 (13 pairs + rem + 9 silu)
  kan_layer_ks<32,4,5,3,SH,129,SM,SM,  9, 18, 7,0,4, true >(hH16, hMfp, hM16, wt + WIN,             bias0a, lane, role);
  kan_layer_ks<65,9,2,1,SM, 64,SH,SH, 19, 38,13,1,9, false>(hM16, hHfp, hH16, wt + WIN + WA,        bias0b, lane, role);
  kan_layer_ks<32,4,5,3,SH,129,SM,SM,  9, 18, 7,0,4, true >(hH16, hMfp, hM16, wt + WIN + WA + WB,   bias1a, lane, role);
  kan_layer_ks<65,9,2,1,SM, 64,SH,SH, 19, 38,13,1,9, false>(hM16, hHfp, hH16, wt + WIN + 2*WA + WB, bias1b, lane, role);

  // final: out = sigmoid(hH @ W_out); each wave does 16 rows, 4 col-chunks/row
  {
    int rr    = (lane & 15) + role*16;
    int chunk = lane >> 4;                   // 0..3 -> cols chunk*16..+15
    float s = 0.0f;
    #pragma unroll
    for (int j = 0; j < 16; ++j)
      s = fmaf((float)hH16[rr*SH + chunk*16 + j], W_out[chunk*16 + j], s);
    s += __shfl_xor(s, 16);
    s += __shfl_xor(s, 32);
    if (lane < 16)
      out[rbase + rr] = __builtin_amdgcn_rcpf(1.0f + __expf(-s));
  }
}

// ---------------------------------------------------------------------------
extern "C" void kernel_launch(void* const* d_in, const int* in_sizes, int n_in,
                              void* d_out, int out_size, void* d_ws, size_t ws_size,
                              hipStream_t stream) {
  const float* x     = (const float*)d_in[0];
  const float* W_in  = (const float*)d_in[1];
  const float* b_in  = (const float*)d_in[2];
  const float* W_out = (const float*)d_in[3];
  const float* c0a = (const float*)d_in[4];  const float* sb0a = (const float*)d_in[5];
  const float* ss0a= (const float*)d_in[6];  const float* bias0a=(const float*)d_in[7];
  const float* c0b = (const float*)d_in[8];  const float* sb0b = (const float*)d_in[9];
  const float* ss0b= (const float*)d_in[10]; const float* bias0b=(const float*)d_in[11];
  const float* c1a = (const float*)d_in[12]; const float* sb1a = (const float*)d_in[13];
  const float* ss1a= (const float*)d_in[14]; const float* bias1a=(const float*)d_in[15];
  const float* c1b = (const float*)d_in[16]; const float* sb1b = (const float*)d_in[17];
  const float* ss1b= (const float*)d_in[18]; const float* bias1b=(const float*)d_in[19];
  float*    out = (float*)d_out;
  _Float16* wt  = (_Float16*)d_ws;       // 675,840 B scratch, repacked every call

  setup_weights<<<(WTOT + 255)/256, 256, 0, stream>>>(
      W_in, c0a, sb0a, ss0a, c0b, sb0b, ss0b,
      c1a, sb1a, ss1a, c1b, sb1b, ss1b, wt);

  kan_forward<<<BATCH/TB, 256, 0, stream>>>(
      x, b_in, W_out, wt, bias0a, bias0b, bias1a, bias1b, out);
}

// Round 8
// 157.970 us; speedup vs baseline: 1.1691x; 1.1691x over previous
//
#include <hip/hip_runtime.h>
#include <math.h>
#include <stdint.h>

// ---------------- model constants ----------------
#define BATCH 65536
#define TB 128           // 4 waves x 32 rows (one 32x32 m-tile each), independent

typedef __fp16   fp16x2  __attribute__((ext_vector_type(2)));   // packed f16 pair
typedef _Float16 half8   __attribute__((ext_vector_type(8)));
typedef float    floatx16 __attribute__((ext_vector_type(16)));

// per-wave LDS strides (halves)
#define SH 68            // hH: 64 cols + 4 pad
#define SM 130           // hM: 129 cols + 1
#define HM_SLICE (32*SM + 64)   // +64 zeroed tail halves (b128 overrun, row 31)

// feat-table: 12 m-rows (m=0..10 real, 11 = zero row) x 66 entries (65 knots
// + 1 pad) x 8 halves. Entry (m,ub) = the 8-slot A-fragment at u = ub/64.
#define FT_ROW 66
#define FT_ENT (12*FT_ROW)      // 792 entries (780 filled)
#define FT_HALVES (FT_ENT*8)    // 6336 halves = 12672 B

// packed-weight geometry (f16), FRAGMENT-ORDERED for 32x32x16:
//   element (ks, nt, lane, j) at ((ks*NT + nt)*512) + lane*8 + j
//   maps to B[k = ks*16 + (lane>>5)*8 + j][n = nt*32 + (lane&31)]
#define WIN 2048          // stage1: 2 ksteps x 2 ntiles x 512
#define KSA 36            // a: 32 spline ksteps + 4 silu
#define KSB 74            // b: 65 spline ksteps (1032 real k) + 9 silu (129 real)
#define WA (KSA*5*512)    // 92160
#define WB (KSB*2*512)    // 75776
#define WTOT (WIN + 2*(WA+WB))   // 337920 halfs = 675840 B of d_ws

// ---------------------------------------------------------------------------
// setup: pack all weights f16 in 32x32-fragment order (unchanged from R0).
// ---------------------------------------------------------------------------
__global__ void setup_weights(
    const float* __restrict__ W_in,
    const float* __restrict__ c0a, const float* __restrict__ sb0a, const float* __restrict__ ss0a,
    const float* __restrict__ c0b, const float* __restrict__ sb0b, const float* __restrict__ ss0b,
    const float* __restrict__ c1a, const float* __restrict__ sb1a, const float* __restrict__ ss1a,
    const float* __restrict__ c1b, const float* __restrict__ sb1b, const float* __restrict__ ss1b,
    _Float16* __restrict__ wt) {
  int idx = blockIdx.x * 256 + threadIdx.x;
  if (idx >= WTOT) return;
  float v = 0.0f;
  if (idx < WIN) {                        // W_in [32][64]: (ks*2+nt)*512 order
    int ks = idx >> 10; int nt = (idx >> 9) & 1;
    int q = idx & 511;  int l = q >> 3;   int j = q & 7;
    int n = nt*32 + (l & 31);
    int k = ks*16 + (l >> 5)*8 + j;
    v = W_in[k*64 + n];
  } else {
    int e2   = idx - WIN;
    int pair = (e2 >= WA + WB) ? 1 : 0;
    int e    = e2 - pair * (WA + WB);
    if (e < WA) {                         // a-type: I=64, O=129 (5 n-tiles)
      const float* coef = pair ? c1a : c0a;
      const float* sb   = pair ? sb1a : sb0a;
      const float* ss   = pair ? ss1a : ss0a;
      int ks = e / 2560; int r = e - ks*2560;
      int nt = r >> 9;   int q = r & 511;
      int l  = q >> 3;   int j = q & 7;
      int n  = nt*32 + (l & 31);
      int k  = ks*16 + (l >> 5)*8 + j;    // k < 576
      if (n < 129) {
        if (k < 512) { int i = k >> 3, p = k & 7; v = ss[i*129+n] * coef[(i*129+n)*8 + p]; }
        else         { int i = k - 512; if (i < 64) v = sb[i*129+n]; }
      }
    } else {                              // b-type: I=129, O=64 (2 n-tiles)
      const float* coef = pair ? c1b : c0b;
      const float* sb   = pair ? sb1b : sb0b;
      const float* ss   = pair ? ss1b : ss0b;
      int eb = e - WA;
      int ks = eb >> 10; int r = eb & 1023;
      int nt = r >> 9;   int q = r & 511;
      int l  = q >> 3;   int j = q & 7;
      int n  = nt*32 + (l & 31);
      int k  = ks*16 + (l >> 5)*8 + j;    // k < 1184
      if (k < 1032)      { int i = k >> 3, p = k & 7; v = ss[i*64+n] * coef[(i*64+n)*8 + p]; }
      else if (k >= 1040){ int s = k - 1040; if (s < 129) v = sb[s*64+n]; }
      // k in [1032,1040) and s >= 129: dead pad slots -> 0
    }
  }
  wt[idx] = (_Float16)v;
}

// ---------------------------------------------------------------------------
// feat8_t: table-driven A-fragment. s=2.5x+5.5, m=floor(s), u=s-m.
// Fragment = lerp between knot entries at u*64. Slot j holds basis_j(x)
// (nonzero at j = m-3..m), identical placement to the old funnel-shift feat8.
// Lerp error <= |w''|max*(2^-6)^2/8 ~ 3e-5  (<< f16 ulp) — accuracy-safe.
// ~19 VALU + 2 ds_read_b128 vs ~35 heavier VALU in the arithmetic version.
// ---------------------------------------------------------------------------
__device__ __forceinline__ half8 feat8_t(float x, const _Float16* __restrict__ ftab) {
  float s   = fmaf(x, 2.5f, 5.5f);
  float mf  = floorf(s);
  float u   = s - mf;
  int   m   = (int)mf;
  unsigned mm = ((unsigned)m <= 10u) ? (unsigned)m : 11u;   // row 11 = zeros
  float uf  = u * 64.0f;
  float ubf = floorf(uf);
  float fr  = uf - ubf;
  int idx = (int)mm * FT_ROW + (int)ubf;                    // ub in [0,63]
  const half8* e = (const half8*)&ftab[idx * 8];
  union { half8 h; fp16x2 p[4]; } T0, T1, R;
  T0.h = e[0];
  T1.h = e[1];
  __fp16 fh = (__fp16)fr;
  fp16x2 f2; f2[0] = fh; f2[1] = fh;
  #pragma unroll
  for (int i = 0; i < 4; ++i)
    R.p[i] = T0.p[i] + f2 * (T1.p[i] - T0.p[i]);            // v_pk_* ops
  return R.h;
}

// extract half #kh of dword w (khs = kh*16), as f32
__device__ __forceinline__ float extract_half(uint32_t w, int khs) {
  union { uint32_t u; _Float16 h[2]; } cv;
  cv.u = w >> khs;
  return (float)cv.h[0];
}

// cheap silu: x * rcp(1+exp(-x)) — v_rcp_f32 (~1 ulp) instead of IEEE div
__device__ __forceinline__ float silu(float x) {
  return x * __builtin_amdgcn_rcpf(1.0f + __expf(-x));
}

// ---------------------------------------------------------------------------
// one KAN layer, per-wave 32 rows = one 32x32 m-tile (R0 structure).
// Spline groups of 8 k-steps: bulk h-read (2x b128), then ALL 8 table-driven
// A-fragments front-loaded (16 ds_reads pipeline together; latency hides
// under the 40 MFMAs), then the MFMA loop with the proven depth-2 zero-copy
// B pipeline. Accumulation order identical to R0.
// ---------------------------------------------------------------------------
template<int KSPL, int KSIL, int NT, int SIN, int O, int SOUT>
__device__ __forceinline__ void kan_layer(
    const _Float16* __restrict__ hinw, _Float16* __restrict__ houtw,
    const _Float16* __restrict__ wt, const float* __restrict__ bias,
    const _Float16* __restrict__ ftab, int lane) {
  constexpr int KTOT = KSPL + KSIL;
  constexpr int NG   = KSPL / 8;            // full spline groups
  constexpr int KR   = KSPL - NG*8;         // remainder spline steps (0 or 1)
  static_assert(KR == 0 || KR == 1, "remainder must be 0/1");
  const int ln  = lane & 31;
  const int kh  = lane >> 5;
  const int khs = kh << 4;
  const half8* __restrict__ bp = (const half8*)wt + lane;   // +lane*16B
  floatx16 acc[NT];
  #pragma unroll
  for (int j = 0; j < NT; ++j)
    #pragma unroll
    for (int e = 0; e < 16; ++e) acc[j][e] = 0.0f;

  half8 B[2][NT];                           // depth-2, zero-copy slots
  #pragma unroll
  for (int d = 0; d < 2; ++d)
    #pragma unroll
    for (int j = 0; j < NT; ++j) B[d][j] = bp[(d*NT + j)*64];

  union H8 { half8 h; uint32_t d[4]; };

  // ---- spline groups: 8 k-steps each; inputs 16g..16g+15 of row ln ----
  #pragma unroll 1
  for (int g = 0; g < NG; ++g) {
    H8 ha, hb;
    ha.h = *(const half8*)&hinw[ln*SIN + g*16];
    hb.h = *(const half8*)&hinw[ln*SIN + g*16 + 8];
    half8 A[8];                              // front-loaded table fragments
    #pragma unroll
    for (int u = 0; u < 8; ++u) {
      uint32_t w = (u < 4) ? ha.d[u] : hb.d[u & 3];
      A[u] = feat8_t(extract_half(w, khs), ftab);  // input i = 2(g*8+u)+kh
    }
    #pragma unroll
    for (int u = 0; u < 8; ++u) {
      #pragma unroll
      for (int j = 0; j < NT; ++j)
        acc[j] = __builtin_amdgcn_mfma_f32_32x32x16_f16(A[u], B[u & 1][j], acc[j], 0, 0, 0);
      #pragma unroll
      for (int j = 0; j < NT; ++j)               // refill same slot with ks+2
        B[u & 1][j] = bp[((g*8 + u + 2)*NT + j)*64];
    }
  }

  // ---- remainder spline step (layer-b: ks = NG*8) ----
  if (KR == 1) {
    constexpr int ks = NG*8;
    uint32_t w = *(const uint32_t*)&hinw[ln*SIN + ks*2];  // elems 2ks,2ks+1
    half8 A = feat8_t(extract_half(w, khs), ftab);
    #pragma unroll
    for (int j = 0; j < NT; ++j)
      acc[j] = __builtin_amdgcn_mfma_f32_32x32x16_f16(A, B[ks & 1][j], acc[j], 0, 0, 0);
    #pragma unroll
    for (int j = 0; j < NT; ++j)
      B[ks & 1][j] = bp[((ks + 2)*NT + j)*64];   // ks+2 < KTOT (KSIL >= 9 here)
  }

  // ---- silu k-steps (fully unrolled; slots compile-time) ----
  #pragma unroll
  for (int sk = 0; sk < KSIL; ++sk) {
    const int ks = KSPL + sk;
    half8 h8 = *(const half8*)&hinw[ln*SIN + sk*16 + kh*8];
    union { fp16x2 h2[4]; half8 v; } Au;
    #pragma unroll
    for (int e = 0; e < 4; ++e) {
      float s0 = silu((float)h8[2*e]);
      float s1 = silu((float)h8[2*e + 1]);
      Au.h2[e] = __builtin_amdgcn_cvt_pkrtz(s0, s1);
    }
    #pragma unroll
    for (int j = 0; j < NT; ++j)
      acc[j] = __builtin_amdgcn_mfma_f32_32x32x16_f16(Au.v, B[ks & 1][j], acc[j], 0, 0, 0);
    const int nks = (ks + 2 < KTOT) ? (ks + 2) : (KTOT - 1);  // clamp: dead loads
    #pragma unroll
    for (int j = 0; j < NT; ++j)
      B[ks & 1][j] = bp[(nks*NT + j)*64];
  }

  // ---- epilogue: C/D col=lane&31, row=(reg&3)+8*(reg>>2)+4*(lane>>5) ----
  #pragma unroll
  for (int j = 0; j < NT; ++j) {
    int col = j*32 + ln;
    if (col < O) {
      float bv = bias[col];
      #pragma unroll
      for (int r = 0; r < 16; ++r) {
        int row = (r & 3) + 8*(r >> 2) + 4*kh;
        houtw[row*SOUT + col] = (_Float16)(acc[j][r] + bv);
      }
    }
  }
}

// ---------------------------------------------------------------------------
// fused forward: R0 structure + LDS feat-table. One barrier (table fill),
// then all waves independent. LDS = 63872 B -> 2 blocks/CU; grid 512 exact.
// ---------------------------------------------------------------------------
extern "C" __global__ void __launch_bounds__(256, 2)
kan_forward(const float* __restrict__ x, const float* __restrict__ b_in,
            const float* __restrict__ W_out, const _Float16* __restrict__ wt,
            const float* __restrict__ bias0a, const float* __restrict__ bias0b,
            const float* __restrict__ bias1a, const float* __restrict__ bias1b,
            float* __restrict__ out) {
  __shared__ _Float16 hM[4][HM_SLICE];
  __shared__ _Float16 hH[4][32*SH];
  __shared__ __align__(16) _Float16 ftab[FT_HALVES];
  const int t    = threadIdx.x;
  const int wv   = t >> 6;
  const int lane = t & 63;
  const int ln   = lane & 31;
  const int kh   = lane >> 5;
  _Float16* hMw = hM[wv];
  _Float16* hHw = hH[wv];
  const int rbase = blockIdx.x * TB + wv * 32;

  // ---- fill feat-table: 780 knot entries (m 0..11, ub 0..64) ----
  for (int e = t; e < 12*65; e += 256) {
    int m  = e / 65;
    int ub = e - m*65;
    float u  = (float)ub * (1.0f/64.0f);
    float t1 = 1.0f - u;
    float w0 = t1*t1*t1*(1.0f/6.0f);
    float w1 = fmaf(u*u, fmaf(0.5f, u, -1.0f), 2.0f/3.0f);   // (3u^3-6u^2+4)/6
    float w2 = fmaf(t1*t1, fmaf(0.5f, t1, -1.0f), 2.0f/3.0f);
    float w3 = u*u*u*(1.0f/6.0f);
    float w[4] = {w0, w1, w2, w3};
    half8 hv;
    #pragma unroll
    for (int j = 0; j < 8; ++j) {
      int k = j - m + 3;                    // basis offset: slot j = basis m-3+k
      float v = (m <= 10 && k >= 0 && k < 4) ? w[k] : 0.0f;
      hv[j] = (_Float16)v;
    }
    *(half8*)&ftab[(m*FT_ROW + ub)*8] = hv;
  }

  // zero hM spots padded reads can touch: col 129 each row + tail pad
  hMw[32*SM + lane] = (_Float16)0.0f;
  if (lane < 32) hMw[lane*SM + 129] = (_Float16)0.0f;
  __syncthreads();                          // table visible to all waves

  // stage 1: hH = relu(x @ W_in + b_in). Two k-steps, 2 n-tiles.
  {
    const float* xr = &x[(rbase + ln)*32 + kh*8];
    float4 v0 = *(const float4*)&xr[0];
    float4 v1 = *(const float4*)&xr[4];
    float4 v2 = *(const float4*)&xr[16];
    float4 v3 = *(const float4*)&xr[20];
    union { fp16x2 h2[4]; half8 h8; } A0, A1;
    A0.h2[0] = __builtin_amdgcn_cvt_pkrtz(v0.x, v0.y);
    A0.h2[1] = __builtin_amdgcn_cvt_pkrtz(v0.z, v0.w);
    A0.h2[2] = __builtin_amdgcn_cvt_pkrtz(v1.x, v1.y);
    A0.h2[3] = __builtin_amdgcn_cvt_pkrtz(v1.z, v1.w);
    A1.h2[0] = __builtin_amdgcn_cvt_pkrtz(v2.x, v2.y);
    A1.h2[1] = __builtin_amdgcn_cvt_pkrtz(v2.z, v2.w);
    A1.h2[2] = __builtin_amdgcn_cvt_pkrtz(v3.x, v3.y);
    A1.h2[3] = __builtin_amdgcn_cvt_pkrtz(v3.z, v3.w);
    const half8* bp = (const half8*)wt + lane;
    #pragma unroll
    for (int nt = 0; nt < 2; ++nt) {
      floatx16 a;
      #pragma unroll
      for (int e = 0; e < 16; ++e) a[e] = 0.0f;
      a = __builtin_amdgcn_mfma_f32_32x32x16_f16(A0.h8, bp[nt*64],       a, 0, 0, 0);
      a = __builtin_amdgcn_mfma_f32_32x32x16_f16(A1.h8, bp[(2 + nt)*64], a, 0, 0, 0);
      int col = nt*32 + ln;
      float bv = b_in[col];
      #pragma unroll
      for (int r = 0; r < 16; ++r) {
        int row = (r & 3) + 8*(r >> 2) + 4*kh;
        hHw[row*SH + col] = (_Float16)fmaxf(a[r] + bv, 0.0f);
      }
    }
  }

  kan_layer<32,4,5,SH,129,SM>(hHw, hMw, wt + WIN,             bias0a, ftab, lane);
  kan_layer<65,9,2,SM, 64,SH>(hMw, hHw, wt + WIN + WA,        bias0b, ftab, lane);
  kan_layer<32,4,5,SH,129,SM>(hHw, hMw, wt + WIN + WA + WB,   bias1a, ftab, lane);
  kan_layer<65,9,2,SM, 64,SH>(hMw, hHw, wt + WIN + 2*WA + WB, bias1b, ftab, lane);

  // final: out = sigmoid(hH @ W_out); two col-halves reduced by shuffle
  {
    float s = 0.0f;
    #pragma unroll
    for (int j = 0; j < 32; ++j)
      s = fmaf((float)hHw[ln*SH + kh*32 + j], W_out[kh*32 + j], s);
    s += __shfl_down(s, 32);
    if (lane < 32)
      out[rbase + ln] = __builtin_amdgcn_rcpf(1.0f + __expf(-s));
  }
}

// ---------------------------------------------------------------------------
extern "C" void kernel_launch(void* const* d_in, const int* in_sizes, int n_in,
                              void* d_out, int out_size, void* d_ws, size_t ws_size,
                              hipStream_t stream) {
  const float* x     = (const float*)d_in[0];
  const float* W_in  = (const float*)d_in[1];
  const float* b_in  = (const float*)d_in[2];
  const float* W_out = (const float*)d_in[3];
  const float* c0a = (const float*)d_in[4];  const float* sb0a = (const float*)d_in[5];
  const float* ss0a= (const float*)d_in[6];  const float* bias0a=(const float*)d_in[7];
  const float* c0b = (const float*)d_in[8];  const float* sb0b = (const float*)d_in[9];
  const float* ss0b= (const float*)d_in[10]; const float* bias0b=(const float*)d_in[11];
  const float* c1a = (const float*)d_in[12]; const float* sb1a = (const float*)d_in[13];
  const float* ss1a= (const float*)d_in[14]; const float* bias1a=(const float*)d_in[15];
  const float* c1b = (const float*)d_in[16]; const float* sb1b = (const float*)d_in[17];
  const float* ss1b= (const float*)d_in[18]; const float* bias1b=(const float*)d_in[19];
  float*    out = (float*)d_out;
  _Float16* wt  = (_Float16*)d_ws;       // 675,840 B scratch, repacked every call

  setup_weights<<<(WTOT + 255)/256, 256, 0, stream>>>(
      W_in, c0a, sb0a, ss0a, c0b, sb0b, ss0b,
      c1a, sb1a, ss1a, c1b, sb1b, ss1b, wt);

  kan_forward<<<BATCH/TB, 256, 0, stream>>>(
      x, b_in, W_out, wt, bias0a, bias0b, bias1a, bias1b, out);
}